// Round 1
// baseline (1344.115 us; speedup 1.0000x reference)
//
#include <hip/hip_runtime.h>
#include <hip/hip_bf16.h>

#define IN_CH 64
#define HID 32
#define HEADS 4
#define OUT_CH 6
#define NEG_SLOPE 0.2f

// ---------------- preprocessing: build dst-CSR ----------------

__global__ void hist_kernel(const int* __restrict__ ei, int E, int N, int* __restrict__ cnt) {
    int e = blockIdx.x * blockDim.x + threadIdx.x;
    int EN = E + N;
    if (e >= EN) return;
    int d = (e < E) ? ei[E + e] : (e - E);   // self-loops appended
    atomicAdd(&cnt[d], 1);
}

__global__ __launch_bounds__(256) void scan_kernel(const int* __restrict__ cnt, int N,
                                                   int* __restrict__ row_start,
                                                   int* __restrict__ cursor) {
    __shared__ int tmp[256];
    int t = threadIdx.x;
    int chunk = (N + 255) >> 8;
    int s0 = t * chunk;
    int s1 = min(s0 + chunk, N);
    int sum = 0;
    for (int i = s0; i < s1; ++i) sum += cnt[i];
    tmp[t] = sum;
    __syncthreads();
    // Hillis-Steele inclusive scan
    for (int off = 1; off < 256; off <<= 1) {
        int v = (t >= off) ? tmp[t - off] : 0;
        __syncthreads();
        tmp[t] += v;
        __syncthreads();
    }
    int run = (t == 0) ? 0 : tmp[t - 1];   // exclusive offset for this chunk
    for (int i = s0; i < s1; ++i) {
        row_start[i] = run;
        cursor[i] = run;
        run += cnt[i];
    }
    if (t == 255) row_start[N] = run;
}

__global__ void scatter_kernel(const int* __restrict__ ei, int E, int N,
                               int* __restrict__ cursor, int* __restrict__ csr_src) {
    int e = blockIdx.x * blockDim.x + threadIdx.x;
    int EN = E + N;
    if (e >= EN) return;
    int s, d;
    if (e < E) { s = ei[e]; d = ei[E + e]; }
    else       { s = e - E; d = s; }
    int pos = atomicAdd(&cursor[d], 1);
    csr_src[pos] = s;
}

// ---------------- GEMM: C[N][128] = A[N][K] @ W[K][128] ----------------

#define BM 32
#define BKK 32

__global__ __launch_bounds__(256) void gemm128_kernel(const float* __restrict__ A,
                                                      const float* __restrict__ W,
                                                      float* __restrict__ C,
                                                      int N, int K) {
    __shared__ float xs[BM][BKK + 1];
    __shared__ float ws[BKK][128];
    int tid = threadIdx.x;
    int r  = tid & 31;
    int cg = tid >> 5;            // 0..7, 16-col group
    int row0 = blockIdx.x * BM;

    float acc[16];
#pragma unroll
    for (int j = 0; j < 16; ++j) acc[j] = 0.f;

    for (int kk = 0; kk < K; kk += BKK) {
        {   // x tile: 32 rows x 32 cols, 4 floats/thread
            int lr = tid >> 3, lc = (tid & 7) * 4;
            int gr = row0 + lr;
            float4 v = make_float4(0.f, 0.f, 0.f, 0.f);
            if (gr < N) v = *reinterpret_cast<const float4*>(A + (size_t)gr * K + kk + lc);
            xs[lr][lc + 0] = v.x; xs[lr][lc + 1] = v.y;
            xs[lr][lc + 2] = v.z; xs[lr][lc + 3] = v.w;
        }
        {   // W tile: 32 rows x 128 cols, 16 floats/thread
            int wr = tid >> 3, wc = (tid & 7) * 16;
            const float4* src = reinterpret_cast<const float4*>(W + (size_t)(kk + wr) * 128 + wc);
            float4* dst = reinterpret_cast<float4*>(&ws[wr][wc]);
#pragma unroll
            for (int i = 0; i < 4; ++i) dst[i] = src[i];
        }
        __syncthreads();
#pragma unroll 8
        for (int k = 0; k < BKK; ++k) {
            float xv = xs[r][k];
            const float4* wrow = reinterpret_cast<const float4*>(&ws[k][cg * 16]);
#pragma unroll
            for (int q = 0; q < 4; ++q) {
                float4 wv = wrow[q];
                acc[q * 4 + 0] += xv * wv.x;
                acc[q * 4 + 1] += xv * wv.y;
                acc[q * 4 + 2] += xv * wv.z;
                acc[q * 4 + 3] += xv * wv.w;
            }
        }
        __syncthreads();
    }
    int gr = row0 + r;
    if (gr < N) {
        float4* out = reinterpret_cast<float4*>(C + (size_t)gr * 128 + cg * 16);
#pragma unroll
        for (int q = 0; q < 4; ++q)
            out[q] = make_float4(acc[q * 4 + 0], acc[q * 4 + 1], acc[q * 4 + 2], acc[q * 4 + 3]);
    }
}

// ---------------- per-node attention logits ----------------

__global__ void al_kernel(const float* __restrict__ h, const float* __restrict__ as,
                          const float* __restrict__ ad, float* __restrict__ als,
                          float* __restrict__ ald, int N) {
    int t = blockIdx.x * blockDim.x + threadIdx.x;
    if (t >= N * 4) return;
    int n = t >> 2, hd = t & 3;
    const float4* hp = reinterpret_cast<const float4*>(h + (size_t)n * 128 + hd * 32);
    const float4* ap = reinterpret_cast<const float4*>(as + hd * 32);
    const float4* dp = reinterpret_cast<const float4*>(ad + hd * 32);
    float s = 0.f, d = 0.f;
#pragma unroll
    for (int i = 0; i < 8; ++i) {
        float4 hv = hp[i], av = ap[i], dv = dp[i];
        s += hv.x * av.x + hv.y * av.y + hv.z * av.z + hv.w * av.w;
        d += hv.x * dv.x + hv.y * dv.y + hv.z * dv.z + hv.w * dv.w;
    }
    als[t] = s;
    ald[t] = d;
}

// ---------------- wave-per-node aggregation (layers 0-2) ----------------

__device__ __forceinline__ float lrelu(float x) { return x > 0.f ? x : NEG_SLOPE * x; }

__global__ __launch_bounds__(256) void agg_kernel(const float* __restrict__ h,
                                                  const float* __restrict__ als,
                                                  const float* __restrict__ ald,
                                                  const int* __restrict__ row_start,
                                                  const int* __restrict__ csr_src,
                                                  const float* __restrict__ bias,
                                                  float* __restrict__ xout,
                                                  int N, int applyElu) {
    int wave = (int)((blockIdx.x * blockDim.x + threadIdx.x) >> 6);
    int lane = threadIdx.x & 63;
    if (wave >= N) return;
    int v = wave;
    int base = row_start[v], end = row_start[v + 1];
    int hd = lane >> 4;            // head 0..3
    int k2 = (lane & 15) * 2;      // dim pair within head

    // pass 1: per-head max of als[src] (lane-parallel over edges)
    float4 mx = make_float4(-1e30f, -1e30f, -1e30f, -1e30f);
    for (int j = base + lane; j < end; j += 64) {
        int s = csr_src[j];
        float4 av = *reinterpret_cast<const float4*>(als + (size_t)s * 4);
        mx.x = fmaxf(mx.x, av.x); mx.y = fmaxf(mx.y, av.y);
        mx.z = fmaxf(mx.z, av.z); mx.w = fmaxf(mx.w, av.w);
    }
#pragma unroll
    for (int off = 32; off; off >>= 1) {
        mx.x = fmaxf(mx.x, __shfl_xor(mx.x, off));
        mx.y = fmaxf(mx.y, __shfl_xor(mx.y, off));
        mx.z = fmaxf(mx.z, __shfl_xor(mx.z, off));
        mx.w = fmaxf(mx.w, __shfl_xor(mx.w, off));
    }
    float aldv = ald[(size_t)v * 4 + hd];
    float alsmax = (hd == 0) ? mx.x : (hd == 1) ? mx.y : (hd == 2) ? mx.z : mx.w;
    float em = lrelu(alsmax + aldv);    // leaky_relu is monotone -> commutes with max

    // pass 2: serial over edges; every lane sees every edge, owns 2 output dims
    float ssum = 0.f;
    float accx = 0.f, accy = 0.f;
    for (int j = base; j < end; ++j) {
        int s = csr_src[j];
        float e = lrelu(als[(size_t)s * 4 + hd] + aldv);
        float ex = __expf(e - em);
        ssum += ex;
        float2 hv = *reinterpret_cast<const float2*>(h + (size_t)s * 128 + hd * 32 + k2);
        accx += ex * hv.x;
        accy += ex * hv.y;
    }
    float inv = 1.0f / (ssum + 1e-16f);
    float2 bv = *reinterpret_cast<const float2*>(bias + hd * 32 + k2);
    float ox = accx * inv + bv.x;
    float oy = accy * inv + bv.y;
    if (applyElu) {
        ox = ox > 0.f ? ox : expm1f(ox);
        oy = oy > 0.f ? oy : expm1f(oy);
    }
    *reinterpret_cast<float2*>(xout + (size_t)v * 128 + hd * 32 + k2) = make_float2(ox, oy);
}

// ---------------- layer 3: GEMM [N,128]x[128,6] with fused al ----------------

__global__ void gemm3_kernel(const float* __restrict__ x, const float* __restrict__ W,
                             const float* __restrict__ as3, const float* __restrict__ ad3,
                             float* __restrict__ h3, float* __restrict__ als3,
                             float* __restrict__ ald3, int N) {
    int n = blockIdx.x * blockDim.x + threadIdx.x;
    if (n >= N) return;
    float acc[6] = {0.f, 0.f, 0.f, 0.f, 0.f, 0.f};
    const float4* xp = reinterpret_cast<const float4*>(x + (size_t)n * 128);
#pragma unroll 4
    for (int k4 = 0; k4 < 32; ++k4) {
        float4 xv = xp[k4];
        const float* w0 = W + (size_t)(k4 * 4) * 6;
#pragma unroll
        for (int j = 0; j < 6; ++j)
            acc[j] += xv.x * w0[j] + xv.y * w0[6 + j] + xv.z * w0[12 + j] + xv.w * w0[18 + j];
    }
    float s = 0.f, d = 0.f;
#pragma unroll
    for (int j = 0; j < 6; ++j) {
        s += acc[j] * as3[j];
        d += acc[j] * ad3[j];
        h3[(size_t)n * 6 + j] = acc[j];
    }
    als3[n] = s;
    ald3[n] = d;
}

__global__ void agg3_kernel(const float* __restrict__ h3, const float* __restrict__ als3,
                            const float* __restrict__ ald3, const int* __restrict__ row_start,
                            const int* __restrict__ csr_src, const float* __restrict__ b3,
                            float* __restrict__ out, int N) {
    int v = blockIdx.x * blockDim.x + threadIdx.x;
    if (v >= N) return;
    int base = row_start[v], end = row_start[v + 1];
    float aldv = ald3[v];
    float mx = -1e30f;
    for (int j = base; j < end; ++j) mx = fmaxf(mx, als3[csr_src[j]]);
    float em = lrelu(mx + aldv);
    float ssum = 0.f;
    float acc[6] = {0.f, 0.f, 0.f, 0.f, 0.f, 0.f};
    for (int j = base; j < end; ++j) {
        int s = csr_src[j];
        float e = lrelu(als3[s] + aldv);
        float ex = __expf(e - em);
        ssum += ex;
        const float* hr = h3 + (size_t)s * 6;
#pragma unroll
        for (int q = 0; q < 6; ++q) acc[q] += ex * hr[q];
    }
    float inv = 1.f / (ssum + 1e-16f);
#pragma unroll
    for (int q = 0; q < 6; ++q) out[(size_t)v * 6 + q] = acc[q] * inv + b3[q];
}

// ---------------- launch ----------------

extern "C" void kernel_launch(void* const* d_in, const int* in_sizes, int n_in,
                              void* d_out, int out_size, void* d_ws, size_t ws_size,
                              hipStream_t stream) {
    const float* x    = (const float*)d_in[0];
    const int*   ei   = (const int*)d_in[1];
    const float* W0   = (const float*)d_in[3];
    const float* as0  = (const float*)d_in[4];
    const float* ad0  = (const float*)d_in[5];
    const float* b0   = (const float*)d_in[6];
    const float* W1   = (const float*)d_in[7];
    const float* as1  = (const float*)d_in[8];
    const float* ad1  = (const float*)d_in[9];
    const float* b1   = (const float*)d_in[10];
    const float* W2   = (const float*)d_in[11];
    const float* as2  = (const float*)d_in[12];
    const float* ad2  = (const float*)d_in[13];
    const float* b2   = (const float*)d_in[14];
    const float* W3   = (const float*)d_in[15];
    const float* as3  = (const float*)d_in[16];
    const float* ad3  = (const float*)d_in[17];
    const float* b3   = (const float*)d_in[18];
    float* out = (float*)d_out;

    int N = in_sizes[0] / IN_CH;
    int E = in_sizes[1] / 2;
    int EN = E + N;

    // workspace layout (256B aligned slices)
    char* p = (char*)d_ws;
    auto alloc = [&](size_t bytes) {
        char* q = p;
        p += (bytes + 255) & ~(size_t)255;
        return q;
    };
    float* hbuf = (float*)alloc((size_t)N * 128 * 4);
    float* xA   = (float*)alloc((size_t)N * 128 * 4);
    float* xB   = (float*)alloc((size_t)N * 128 * 4);
    float* als  = (float*)alloc((size_t)N * 4 * 4);
    float* ald  = (float*)alloc((size_t)N * 4 * 4);
    float* h3   = (float*)alloc((size_t)N * 6 * 4);
    float* als3 = (float*)alloc((size_t)N * 4);
    float* ald3 = (float*)alloc((size_t)N * 4);
    int* row_start = (int*)alloc((size_t)(N + 1) * 4);
    int* cursor    = (int*)alloc((size_t)N * 4);
    int* csr_src   = (int*)alloc((size_t)EN * 4);
    (void)ws_size; (void)n_in; (void)out_size;

    // ---- build CSR by dst ----
    hipMemsetAsync(cursor, 0, (size_t)N * 4, stream);
    hist_kernel<<<(EN + 255) / 256, 256, 0, stream>>>(ei, E, N, cursor);
    scan_kernel<<<1, 256, 0, stream>>>(cursor, N, row_start, cursor);
    // NOTE: scan reads cnt==cursor then rewrites cursor with offsets (same buffer is safe:
    // each thread reads its chunk fully before writing it in the second sweep).
    scatter_kernel<<<(EN + 255) / 256, 256, 0, stream>>>(ei, E, N, cursor, csr_src);

    int gemm_grid = (N + BM - 1) / BM;
    int al_grid   = (N * 4 + 255) / 256;
    int agg_grid  = (N + 3) / 4;      // 4 waves/block, 1 wave/node
    int n_grid    = (N + 255) / 256;

    // ---- layer 0: 64 -> 4x32, ELU ----
    gemm128_kernel<<<gemm_grid, 256, 0, stream>>>(x, W0, hbuf, N, 64);
    al_kernel<<<al_grid, 256, 0, stream>>>(hbuf, as0, ad0, als, ald, N);
    agg_kernel<<<agg_grid, 256, 0, stream>>>(hbuf, als, ald, row_start, csr_src, b0, xA, N, 1);

    // ---- layer 1 ----
    gemm128_kernel<<<gemm_grid, 256, 0, stream>>>(xA, W1, hbuf, N, 128);
    al_kernel<<<al_grid, 256, 0, stream>>>(hbuf, as1, ad1, als, ald, N);
    agg_kernel<<<agg_grid, 256, 0, stream>>>(hbuf, als, ald, row_start, csr_src, b1, xB, N, 1);

    // ---- layer 2 ----
    gemm128_kernel<<<gemm_grid, 256, 0, stream>>>(xB, W2, hbuf, N, 128);
    al_kernel<<<al_grid, 256, 0, stream>>>(hbuf, as2, ad2, als, ald, N);
    agg_kernel<<<agg_grid, 256, 0, stream>>>(hbuf, als, ald, row_start, csr_src, b2, xA, N, 1);

    // ---- layer 3: 128 -> 6, 1 head, no ELU ----
    gemm3_kernel<<<n_grid, 256, 0, stream>>>(xA, W3, as3, ad3, h3, als3, ald3, N);
    agg3_kernel<<<n_grid, 256, 0, stream>>>(h3, als3, ald3, row_start, csr_src, b3, out, N);
}

// Round 2
// 1124.609 us; speedup vs baseline: 1.1952x; 1.1952x over previous
//
#include <hip/hip_runtime.h>
#include <hip/hip_bf16.h>

#define IN_CH 64
#define HID 32
#define HEADS 4
#define OUT_CH 6
#define NEG_SLOPE 0.2f

// ---------------- preprocessing: build dst-CSR ----------------

__global__ void hist_kernel(const int* __restrict__ ei, int E, int N, int* __restrict__ cnt) {
    int e = blockIdx.x * blockDim.x + threadIdx.x;
    int EN = E + N;
    if (e >= EN) return;
    int d = (e < E) ? ei[E + e] : (e - E);   // self-loops appended
    atomicAdd(&cnt[d], 1);
}

// ---- multi-block scan: partial sums -> scan sums -> apply ----
#define SCAN_ELEMS 1024

__global__ __launch_bounds__(256) void scan_partial(const int* __restrict__ cnt, int N,
                                                    int* __restrict__ blocksum) {
    __shared__ int red[256];
    int t = threadIdx.x;
    int b0 = blockIdx.x * SCAN_ELEMS;
    int sum = 0;
#pragma unroll
    for (int i = 0; i < SCAN_ELEMS / 256; ++i) {
        int g = b0 + t + i * 256;
        sum += (g < N) ? cnt[g] : 0;
    }
    red[t] = sum;
    __syncthreads();
    for (int off = 128; off; off >>= 1) {
        if (t < off) red[t] += red[t + off];
        __syncthreads();
    }
    if (t == 0) blocksum[blockIdx.x] = red[0];
}

__global__ __launch_bounds__(256) void scan_sums(int* __restrict__ blocksum, int nb) {
    __shared__ int tmp[256];
    int t = threadIdx.x;
    int chunk = (nb + 255) >> 8;
    int s0 = t * chunk, s1 = min(s0 + chunk, nb);
    int sum = 0;
    for (int i = s0; i < s1; ++i) sum += blocksum[i];
    tmp[t] = sum;
    __syncthreads();
    for (int off = 1; off < 256; off <<= 1) {
        int v = (t >= off) ? tmp[t - off] : 0;
        __syncthreads();
        tmp[t] += v;
        __syncthreads();
    }
    int run = (t == 0) ? 0 : tmp[t - 1];
    for (int i = s0; i < s1; ++i) {
        int c = blocksum[i];
        blocksum[i] = run;
        run += c;
    }
}

__global__ __launch_bounds__(256) void scan_apply(const int* __restrict__ cnt, int N, int total,
                                                  const int* __restrict__ blocksum,
                                                  int* __restrict__ row_start,
                                                  int* __restrict__ cursor) {
    __shared__ int tmp[256];
    int t = threadIdx.x;
    int g = blockIdx.x * SCAN_ELEMS + t * 4;
    int4 c = make_int4(0, 0, 0, 0);
    if (g + 3 < N) {
        c = *reinterpret_cast<const int4*>(cnt + g);
    } else {
        if (g + 0 < N) c.x = cnt[g + 0];
        if (g + 1 < N) c.y = cnt[g + 1];
        if (g + 2 < N) c.z = cnt[g + 2];
        if (g + 3 < N) c.w = cnt[g + 3];
    }
    tmp[t] = c.x + c.y + c.z + c.w;
    __syncthreads();
    for (int off = 1; off < 256; off <<= 1) {
        int v = (t >= off) ? tmp[t - off] : 0;
        __syncthreads();
        tmp[t] += v;
        __syncthreads();
    }
    int4 rs;
    rs.x = blocksum[blockIdx.x] + ((t == 0) ? 0 : tmp[t - 1]);
    rs.y = rs.x + c.x;
    rs.z = rs.y + c.y;
    rs.w = rs.z + c.z;
    if (g + 3 < N) {
        *reinterpret_cast<int4*>(row_start + g) = rs;
        *reinterpret_cast<int4*>(cursor + g) = rs;
    } else {
        if (g + 0 < N) { row_start[g + 0] = rs.x; cursor[g + 0] = rs.x; }
        if (g + 1 < N) { row_start[g + 1] = rs.y; cursor[g + 1] = rs.y; }
        if (g + 2 < N) { row_start[g + 2] = rs.z; cursor[g + 2] = rs.z; }
        if (g + 3 < N) { row_start[g + 3] = rs.w; cursor[g + 3] = rs.w; }
    }
    if (blockIdx.x == 0 && t == 0) row_start[N] = total;   // total known analytically (E+N)
}

__global__ void scatter_kernel(const int* __restrict__ ei, int E, int N,
                               int* __restrict__ cursor, int* __restrict__ csr_src) {
    int e = blockIdx.x * blockDim.x + threadIdx.x;
    int EN = E + N;
    if (e >= EN) return;
    int s, d;
    if (e < E) { s = ei[e]; d = ei[E + e]; }
    else       { s = e - E; d = s; }
    int pos = atomicAdd(&cursor[d], 1);
    csr_src[pos] = s;
}

// ---------------- GEMM: C[N][128] = A[N][K] @ W[K][128] ----------------

#define BM 32
#define BKK 32

__global__ __launch_bounds__(256) void gemm128_kernel(const float* __restrict__ A,
                                                      const float* __restrict__ W,
                                                      float* __restrict__ C,
                                                      int N, int K) {
    __shared__ float xs[BM][BKK + 1];
    __shared__ float ws[BKK][128];
    int tid = threadIdx.x;
    int r  = tid & 31;
    int cg = tid >> 5;            // 0..7, 16-col group
    int row0 = blockIdx.x * BM;

    float acc[16];
#pragma unroll
    for (int j = 0; j < 16; ++j) acc[j] = 0.f;

    for (int kk = 0; kk < K; kk += BKK) {
        {   // x tile: 32 rows x 32 cols, 4 floats/thread
            int lr = tid >> 3, lc = (tid & 7) * 4;
            int gr = row0 + lr;
            float4 v = make_float4(0.f, 0.f, 0.f, 0.f);
            if (gr < N) v = *reinterpret_cast<const float4*>(A + (size_t)gr * K + kk + lc);
            xs[lr][lc + 0] = v.x; xs[lr][lc + 1] = v.y;
            xs[lr][lc + 2] = v.z; xs[lr][lc + 3] = v.w;
        }
        {   // W tile: 32 rows x 128 cols, 16 floats/thread
            int wr = tid >> 3, wc = (tid & 7) * 16;
            const float4* src = reinterpret_cast<const float4*>(W + (size_t)(kk + wr) * 128 + wc);
            float4* dst = reinterpret_cast<float4*>(&ws[wr][wc]);
#pragma unroll
            for (int i = 0; i < 4; ++i) dst[i] = src[i];
        }
        __syncthreads();
#pragma unroll 8
        for (int k = 0; k < BKK; ++k) {
            float xv = xs[r][k];
            const float4* wrow = reinterpret_cast<const float4*>(&ws[k][cg * 16]);
#pragma unroll
            for (int q = 0; q < 4; ++q) {
                float4 wv = wrow[q];
                acc[q * 4 + 0] += xv * wv.x;
                acc[q * 4 + 1] += xv * wv.y;
                acc[q * 4 + 2] += xv * wv.z;
                acc[q * 4 + 3] += xv * wv.w;
            }
        }
        __syncthreads();
    }
    int gr = row0 + r;
    if (gr < N) {
        float4* out = reinterpret_cast<float4*>(C + (size_t)gr * 128 + cg * 16);
#pragma unroll
        for (int q = 0; q < 4; ++q)
            out[q] = make_float4(acc[q * 4 + 0], acc[q * 4 + 1], acc[q * 4 + 2], acc[q * 4 + 3]);
    }
}

// ---------------- per-node attention logits ----------------

__global__ void al_kernel(const float* __restrict__ h, const float* __restrict__ as,
                          const float* __restrict__ ad, float* __restrict__ als,
                          float* __restrict__ ald, int N) {
    int t = blockIdx.x * blockDim.x + threadIdx.x;
    if (t >= N * 4) return;
    int n = t >> 2, hd = t & 3;
    const float4* hp = reinterpret_cast<const float4*>(h + (size_t)n * 128 + hd * 32);
    const float4* ap = reinterpret_cast<const float4*>(as + hd * 32);
    const float4* dp = reinterpret_cast<const float4*>(ad + hd * 32);
    float s = 0.f, d = 0.f;
#pragma unroll
    for (int i = 0; i < 8; ++i) {
        float4 hv = hp[i], av = ap[i], dv = dp[i];
        s += hv.x * av.x + hv.y * av.y + hv.z * av.z + hv.w * av.w;
        d += hv.x * dv.x + hv.y * dv.y + hv.z * dv.z + hv.w * dv.w;
    }
    als[t] = s;
    ald[t] = d;
}

// ---------------- wave-per-node aggregation (layers 0-2) ----------------

__device__ __forceinline__ float lrelu(float x) { return x > 0.f ? x : NEG_SLOPE * x; }

__global__ __launch_bounds__(256) void agg_kernel(const float* __restrict__ h,
                                                  const float* __restrict__ als,
                                                  const float* __restrict__ ald,
                                                  const int* __restrict__ row_start,
                                                  const int* __restrict__ csr_src,
                                                  const float* __restrict__ bias,
                                                  float* __restrict__ xout,
                                                  int N, int applyElu) {
    int wave = (int)((blockIdx.x * blockDim.x + threadIdx.x) >> 6);
    int lane = threadIdx.x & 63;
    if (wave >= N) return;
    int v = wave;
    int base = row_start[v], end = row_start[v + 1];
    int hd = lane >> 4;            // head 0..3
    int k2 = (lane & 15) * 2;      // dim pair within head

    // pass 1: per-head max of als[src] (lane-parallel over edges)
    float4 mx = make_float4(-1e30f, -1e30f, -1e30f, -1e30f);
    for (int j = base + lane; j < end; j += 64) {
        int s = csr_src[j];
        float4 av = *reinterpret_cast<const float4*>(als + (size_t)s * 4);
        mx.x = fmaxf(mx.x, av.x); mx.y = fmaxf(mx.y, av.y);
        mx.z = fmaxf(mx.z, av.z); mx.w = fmaxf(mx.w, av.w);
    }
#pragma unroll
    for (int off = 32; off; off >>= 1) {
        mx.x = fmaxf(mx.x, __shfl_xor(mx.x, off));
        mx.y = fmaxf(mx.y, __shfl_xor(mx.y, off));
        mx.z = fmaxf(mx.z, __shfl_xor(mx.z, off));
        mx.w = fmaxf(mx.w, __shfl_xor(mx.w, off));
    }
    float aldv = ald[(size_t)v * 4 + hd];
    float alsmax = (hd == 0) ? mx.x : (hd == 1) ? mx.y : (hd == 2) ? mx.z : mx.w;
    float em = lrelu(alsmax + aldv);    // leaky_relu is monotone -> commutes with max

    // pass 2: serial over edges; every lane sees every edge, owns 2 output dims
    float ssum = 0.f;
    float accx = 0.f, accy = 0.f;
    for (int j = base; j < end; ++j) {
        int s = csr_src[j];
        float e = lrelu(als[(size_t)s * 4 + hd] + aldv);
        float ex = __expf(e - em);
        ssum += ex;
        float2 hv = *reinterpret_cast<const float2*>(h + (size_t)s * 128 + hd * 32 + k2);
        accx += ex * hv.x;
        accy += ex * hv.y;
    }
    float inv = 1.0f / (ssum + 1e-16f);
    float2 bv = *reinterpret_cast<const float2*>(bias + hd * 32 + k2);
    float ox = accx * inv + bv.x;
    float oy = accy * inv + bv.y;
    if (applyElu) {
        ox = ox > 0.f ? ox : expm1f(ox);
        oy = oy > 0.f ? oy : expm1f(oy);
    }
    *reinterpret_cast<float2*>(xout + (size_t)v * 128 + hd * 32 + k2) = make_float2(ox, oy);
}

// ---------------- layer 3: GEMM [N,128]x[128,6] with fused al ----------------

__global__ void gemm3_kernel(const float* __restrict__ x, const float* __restrict__ W,
                             const float* __restrict__ as3, const float* __restrict__ ad3,
                             float* __restrict__ h3, float* __restrict__ als3,
                             float* __restrict__ ald3, int N) {
    int n = blockIdx.x * blockDim.x + threadIdx.x;
    if (n >= N) return;
    float acc[6] = {0.f, 0.f, 0.f, 0.f, 0.f, 0.f};
    const float4* xp = reinterpret_cast<const float4*>(x + (size_t)n * 128);
#pragma unroll 4
    for (int k4 = 0; k4 < 32; ++k4) {
        float4 xv = xp[k4];
        const float* w0 = W + (size_t)(k4 * 4) * 6;
#pragma unroll
        for (int j = 0; j < 6; ++j)
            acc[j] += xv.x * w0[j] + xv.y * w0[6 + j] + xv.z * w0[12 + j] + xv.w * w0[18 + j];
    }
    float s = 0.f, d = 0.f;
#pragma unroll
    for (int j = 0; j < 6; ++j) {
        s += acc[j] * as3[j];
        d += acc[j] * ad3[j];
        h3[(size_t)n * 6 + j] = acc[j];
    }
    als3[n] = s;
    ald3[n] = d;
}

__global__ void agg3_kernel(const float* __restrict__ h3, const float* __restrict__ als3,
                            const float* __restrict__ ald3, const int* __restrict__ row_start,
                            const int* __restrict__ csr_src, const float* __restrict__ b3,
                            float* __restrict__ out, int N) {
    int v = blockIdx.x * blockDim.x + threadIdx.x;
    if (v >= N) return;
    int base = row_start[v], end = row_start[v + 1];
    float aldv = ald3[v];
    float mx = -1e30f;
    for (int j = base; j < end; ++j) mx = fmaxf(mx, als3[csr_src[j]]);
    float em = lrelu(mx + aldv);
    float ssum = 0.f;
    float acc[6] = {0.f, 0.f, 0.f, 0.f, 0.f, 0.f};
    for (int j = base; j < end; ++j) {
        int s = csr_src[j];
        float e = lrelu(als3[s] + aldv);
        float ex = __expf(e - em);
        ssum += ex;
        const float* hr = h3 + (size_t)s * 6;
#pragma unroll
        for (int q = 0; q < 6; ++q) acc[q] += ex * hr[q];
    }
    float inv = 1.f / (ssum + 1e-16f);
#pragma unroll
    for (int q = 0; q < 6; ++q) out[(size_t)v * 6 + q] = acc[q] * inv + b3[q];
}

// ---------------- launch ----------------

extern "C" void kernel_launch(void* const* d_in, const int* in_sizes, int n_in,
                              void* d_out, int out_size, void* d_ws, size_t ws_size,
                              hipStream_t stream) {
    const float* x    = (const float*)d_in[0];
    const int*   ei   = (const int*)d_in[1];
    const float* W0   = (const float*)d_in[3];
    const float* as0  = (const float*)d_in[4];
    const float* ad0  = (const float*)d_in[5];
    const float* b0   = (const float*)d_in[6];
    const float* W1   = (const float*)d_in[7];
    const float* as1  = (const float*)d_in[8];
    const float* ad1  = (const float*)d_in[9];
    const float* b1   = (const float*)d_in[10];
    const float* W2   = (const float*)d_in[11];
    const float* as2  = (const float*)d_in[12];
    const float* ad2  = (const float*)d_in[13];
    const float* b2   = (const float*)d_in[14];
    const float* W3   = (const float*)d_in[15];
    const float* as3  = (const float*)d_in[16];
    const float* ad3  = (const float*)d_in[17];
    const float* b3   = (const float*)d_in[18];
    float* out = (float*)d_out;

    int N = in_sizes[0] / IN_CH;
    int E = in_sizes[1] / 2;
    int EN = E + N;

    // workspace layout (256B aligned slices)
    char* p = (char*)d_ws;
    auto alloc = [&](size_t bytes) {
        char* q = p;
        p += (bytes + 255) & ~(size_t)255;
        return q;
    };
    float* hbuf = (float*)alloc((size_t)N * 128 * 4);
    float* xA   = (float*)alloc((size_t)N * 128 * 4);
    float* xB   = (float*)alloc((size_t)N * 128 * 4);
    float* als  = (float*)alloc((size_t)N * 4 * 4);
    float* ald  = (float*)alloc((size_t)N * 4 * 4);
    float* h3   = (float*)alloc((size_t)N * 6 * 4);
    float* als3 = (float*)alloc((size_t)N * 4);
    float* ald3 = (float*)alloc((size_t)N * 4);
    int* row_start = (int*)alloc((size_t)(N + 1) * 4);
    int* cursor    = (int*)alloc((size_t)N * 4);
    int* csr_src   = (int*)alloc((size_t)EN * 4);
    int* blocksum  = (int*)alloc((size_t)4096 * 4);
    (void)ws_size; (void)n_in; (void)out_size;

    // ---- build CSR by dst ----
    hipMemsetAsync(cursor, 0, (size_t)N * 4, stream);
    hist_kernel<<<(EN + 255) / 256, 256, 0, stream>>>(ei, E, N, cursor);
    int nb = (N + SCAN_ELEMS - 1) / SCAN_ELEMS;
    scan_partial<<<nb, 256, 0, stream>>>(cursor, N, blocksum);
    scan_sums<<<1, 256, 0, stream>>>(blocksum, nb);
    scan_apply<<<nb, 256, 0, stream>>>(cursor, N, EN, blocksum, row_start, cursor);
    scatter_kernel<<<(EN + 255) / 256, 256, 0, stream>>>(ei, E, N, cursor, csr_src);

    int gemm_grid = (N + BM - 1) / BM;
    int al_grid   = (N * 4 + 255) / 256;
    int agg_grid  = (N + 3) / 4;      // 4 waves/block, 1 wave/node
    int n_grid    = (N + 255) / 256;

    // ---- layer 0: 64 -> 4x32, ELU ----
    gemm128_kernel<<<gemm_grid, 256, 0, stream>>>(x, W0, hbuf, N, 64);
    al_kernel<<<al_grid, 256, 0, stream>>>(hbuf, as0, ad0, als, ald, N);
    agg_kernel<<<agg_grid, 256, 0, stream>>>(hbuf, als, ald, row_start, csr_src, b0, xA, N, 1);

    // ---- layer 1 ----
    gemm128_kernel<<<gemm_grid, 256, 0, stream>>>(xA, W1, hbuf, N, 128);
    al_kernel<<<al_grid, 256, 0, stream>>>(hbuf, as1, ad1, als, ald, N);
    agg_kernel<<<agg_grid, 256, 0, stream>>>(hbuf, als, ald, row_start, csr_src, b1, xB, N, 1);

    // ---- layer 2 ----
    gemm128_kernel<<<gemm_grid, 256, 0, stream>>>(xB, W2, hbuf, N, 128);
    al_kernel<<<al_grid, 256, 0, stream>>>(hbuf, as2, ad2, als, ald, N);
    agg_kernel<<<agg_grid, 256, 0, stream>>>(hbuf, als, ald, row_start, csr_src, b2, xA, N, 1);

    // ---- layer 3: 128 -> 6, 1 head, no ELU ----
    gemm3_kernel<<<n_grid, 256, 0, stream>>>(xA, W3, as3, ad3, h3, als3, ald3, N);
    agg3_kernel<<<n_grid, 256, 0, stream>>>(h3, als3, ald3, row_start, csr_src, b3, out, N);
}

// Round 3
// 863.993 us; speedup vs baseline: 1.5557x; 1.3016x over previous
//
#include <hip/hip_runtime.h>
#include <hip/hip_bf16.h>

#define IN_CH 64
#define HID 32
#define HEADS 4
#define OUT_CH 6
#define NEG_SLOPE 0.2f

// ---------------- preprocessing: build dst-CSR ----------------

__global__ void hist_kernel(const int* __restrict__ ei, int E, int N, int* __restrict__ cnt) {
    int e = blockIdx.x * blockDim.x + threadIdx.x;
    int EN = E + N;
    if (e >= EN) return;
    int d = (e < E) ? ei[E + e] : (e - E);   // self-loops appended
    atomicAdd(&cnt[d], 1);
}

// ---- multi-block scan: partial sums -> scan sums -> apply ----
#define SCAN_ELEMS 1024

__global__ __launch_bounds__(256) void scan_partial(const int* __restrict__ cnt, int N,
                                                    int* __restrict__ blocksum) {
    __shared__ int red[256];
    int t = threadIdx.x;
    int b0 = blockIdx.x * SCAN_ELEMS;
    int sum = 0;
#pragma unroll
    for (int i = 0; i < SCAN_ELEMS / 256; ++i) {
        int g = b0 + t + i * 256;
        sum += (g < N) ? cnt[g] : 0;
    }
    red[t] = sum;
    __syncthreads();
    for (int off = 128; off; off >>= 1) {
        if (t < off) red[t] += red[t + off];
        __syncthreads();
    }
    if (t == 0) blocksum[blockIdx.x] = red[0];
}

__global__ __launch_bounds__(256) void scan_sums(int* __restrict__ blocksum, int nb) {
    __shared__ int tmp[256];
    int t = threadIdx.x;
    int chunk = (nb + 255) >> 8;
    int s0 = t * chunk, s1 = min(s0 + chunk, nb);
    int sum = 0;
    for (int i = s0; i < s1; ++i) sum += blocksum[i];
    tmp[t] = sum;
    __syncthreads();
    for (int off = 1; off < 256; off <<= 1) {
        int v = (t >= off) ? tmp[t - off] : 0;
        __syncthreads();
        tmp[t] += v;
        __syncthreads();
    }
    int run = (t == 0) ? 0 : tmp[t - 1];
    for (int i = s0; i < s1; ++i) {
        int c = blocksum[i];
        blocksum[i] = run;
        run += c;
    }
}

__global__ __launch_bounds__(256) void scan_apply(const int* __restrict__ cnt, int N, int total,
                                                  const int* __restrict__ blocksum,
                                                  int* __restrict__ row_start,
                                                  int* __restrict__ cursor) {
    __shared__ int tmp[256];
    int t = threadIdx.x;
    int g = blockIdx.x * SCAN_ELEMS + t * 4;
    int4 c = make_int4(0, 0, 0, 0);
    if (g + 3 < N) {
        c = *reinterpret_cast<const int4*>(cnt + g);
    } else {
        if (g + 0 < N) c.x = cnt[g + 0];
        if (g + 1 < N) c.y = cnt[g + 1];
        if (g + 2 < N) c.z = cnt[g + 2];
        if (g + 3 < N) c.w = cnt[g + 3];
    }
    tmp[t] = c.x + c.y + c.z + c.w;
    __syncthreads();
    for (int off = 1; off < 256; off <<= 1) {
        int v = (t >= off) ? tmp[t - off] : 0;
        __syncthreads();
        tmp[t] += v;
        __syncthreads();
    }
    int4 rs;
    rs.x = blocksum[blockIdx.x] + ((t == 0) ? 0 : tmp[t - 1]);
    rs.y = rs.x + c.x;
    rs.z = rs.y + c.y;
    rs.w = rs.z + c.z;
    if (g + 3 < N) {
        *reinterpret_cast<int4*>(row_start + g) = rs;
        *reinterpret_cast<int4*>(cursor + g) = rs;
    } else {
        if (g + 0 < N) { row_start[g + 0] = rs.x; cursor[g + 0] = rs.x; }
        if (g + 1 < N) { row_start[g + 1] = rs.y; cursor[g + 1] = rs.y; }
        if (g + 2 < N) { row_start[g + 2] = rs.z; cursor[g + 2] = rs.z; }
        if (g + 3 < N) { row_start[g + 3] = rs.w; cursor[g + 3] = rs.w; }
    }
    if (blockIdx.x == 0 && t == 0) row_start[N] = total;   // total known analytically (E+N)
}

__global__ void scatter_kernel(const int* __restrict__ ei, int E, int N,
                               int* __restrict__ cursor, int* __restrict__ csr_src) {
    int e = blockIdx.x * blockDim.x + threadIdx.x;
    int EN = E + N;
    if (e >= EN) return;
    int s, d;
    if (e < E) { s = ei[e]; d = ei[E + e]; }
    else       { s = e - E; d = s; }
    int pos = atomicAdd(&cursor[d], 1);
    csr_src[pos] = s;
}

// ------- GEMM: C[N][128] = A[N][K] @ W[K][128], fused als/ald epilogue -------

#define BM 32
#define BKK 32

__global__ __launch_bounds__(256) void gemm128_kernel(const float* __restrict__ A,
                                                      const float* __restrict__ W,
                                                      const float* __restrict__ avs,
                                                      const float* __restrict__ avd,
                                                      float* __restrict__ C,
                                                      float* __restrict__ als,
                                                      float* __restrict__ ald,
                                                      int N, int K) {
    __shared__ float xs[BM][BKK + 1];
    __shared__ float ws[BKK][128];
    __shared__ float red_s[BM][9];
    __shared__ float red_d[BM][9];
    int tid = threadIdx.x;
    int r  = tid & 31;
    int cg = tid >> 5;            // 0..7, 16-col group
    int row0 = blockIdx.x * BM;

    float acc[16];
#pragma unroll
    for (int j = 0; j < 16; ++j) acc[j] = 0.f;

    for (int kk = 0; kk < K; kk += BKK) {
        {   // x tile: 32 rows x 32 cols, 4 floats/thread
            int lr = tid >> 3, lc = (tid & 7) * 4;
            int gr = row0 + lr;
            float4 v = make_float4(0.f, 0.f, 0.f, 0.f);
            if (gr < N) v = *reinterpret_cast<const float4*>(A + (size_t)gr * K + kk + lc);
            xs[lr][lc + 0] = v.x; xs[lr][lc + 1] = v.y;
            xs[lr][lc + 2] = v.z; xs[lr][lc + 3] = v.w;
        }
        {   // W tile: 32 rows x 128 cols, 16 floats/thread
            int wr = tid >> 3, wc = (tid & 7) * 16;
            const float4* src = reinterpret_cast<const float4*>(W + (size_t)(kk + wr) * 128 + wc);
            float4* dst = reinterpret_cast<float4*>(&ws[wr][wc]);
#pragma unroll
            for (int i = 0; i < 4; ++i) dst[i] = src[i];
        }
        __syncthreads();
#pragma unroll 8
        for (int k = 0; k < BKK; ++k) {
            float xv = xs[r][k];
            const float4* wrow = reinterpret_cast<const float4*>(&ws[k][cg * 16]);
#pragma unroll
            for (int q = 0; q < 4; ++q) {
                float4 wv = wrow[q];
                acc[q * 4 + 0] += xv * wv.x;
                acc[q * 4 + 1] += xv * wv.y;
                acc[q * 4 + 2] += xv * wv.z;
                acc[q * 4 + 3] += xv * wv.w;
            }
        }
        __syncthreads();
    }
    int gr = row0 + r;
    if (gr < N) {
        float4* out = reinterpret_cast<float4*>(C + (size_t)gr * 128 + cg * 16);
#pragma unroll
        for (int q = 0; q < 4; ++q)
            out[q] = make_float4(acc[q * 4 + 0], acc[q * 4 + 1], acc[q * 4 + 2], acc[q * 4 + 3]);
    }
    // fused attention-logit partials: als[n][hd] = sum_d h[n][hd][d]*as[hd][d]
    {
        float ps = 0.f, pd = 0.f;
#pragma unroll
        for (int q = 0; q < 16; ++q) {
            float a = acc[q];
            ps += a * avs[cg * 16 + q];
            pd += a * avd[cg * 16 + q];
        }
        red_s[r][cg] = ps;
        red_d[r][cg] = pd;
        __syncthreads();
        if (gr < N) {
            if (cg < 4) {
                als[(size_t)gr * 4 + cg] = red_s[r][2 * cg] + red_s[r][2 * cg + 1];
            } else {
                int hd = cg - 4;
                ald[(size_t)gr * 4 + hd] = red_d[r][2 * hd] + red_d[r][2 * hd + 1];
            }
        }
    }
}

// ---------------- wave-per-node aggregation (layers 0-2) ----------------

__device__ __forceinline__ float lrelu(float x) { return x > 0.f ? x : NEG_SLOPE * x; }

__global__ __launch_bounds__(256) void agg_kernel(const float* __restrict__ h,
                                                  const float* __restrict__ als4,
                                                  const float* __restrict__ ald4,
                                                  const int* __restrict__ row_start,
                                                  const int* __restrict__ csr_src,
                                                  const float* __restrict__ bias,
                                                  float* __restrict__ xout,
                                                  int N, int applyElu) {
    __shared__ float ex_s[4][256];   // [waveInBlock][edge*4+head]
    __shared__ int   ss_s[4][64];    // [waveInBlock][edge]
    int w = threadIdx.x >> 6;
    int wave = blockIdx.x * 4 + w;
    int lane = threadIdx.x & 63;
    if (wave >= N) return;
    int v = wave;
    int base = row_start[v], end = row_start[v + 1];
    int deg = end - base;
    int hd = lane >> 4;            // head 0..3
    int k2 = (lane & 15) * 2;      // dim pair within head

    float4 aldv4 = *reinterpret_cast<const float4*>(ald4 + (size_t)v * 4);

    // ---- chunk-0 lane-parallel loads (reused below when deg <= 64) ----
    int j0 = base + lane;
    bool v0 = j0 < end;
    int s0 = v0 ? csr_src[j0] : 0;
    float4 a0 = make_float4(-1e30f, -1e30f, -1e30f, -1e30f);
    if (v0) a0 = *reinterpret_cast<const float4*>(als4 + (size_t)s0 * 4);

    float4 mx = a0;
    if (deg > 64) {   // rare slow pre-pass for the max
        for (int j = base + lane + 64; j < end; j += 64) {
            int s = csr_src[j];
            float4 a = *reinterpret_cast<const float4*>(als4 + (size_t)s * 4);
            mx.x = fmaxf(mx.x, a.x); mx.y = fmaxf(mx.y, a.y);
            mx.z = fmaxf(mx.z, a.z); mx.w = fmaxf(mx.w, a.w);
        }
    }
#pragma unroll
    for (int off = 32; off; off >>= 1) {
        mx.x = fmaxf(mx.x, __shfl_xor(mx.x, off));
        mx.y = fmaxf(mx.y, __shfl_xor(mx.y, off));
        mx.z = fmaxf(mx.z, __shfl_xor(mx.z, off));
        mx.w = fmaxf(mx.w, __shfl_xor(mx.w, off));
    }
    // leaky_relu monotone + ald const per node => em = lrelu(max(als)+ald)
    float4 em4;
    em4.x = lrelu(mx.x + aldv4.x);
    em4.y = lrelu(mx.y + aldv4.y);
    em4.z = lrelu(mx.z + aldv4.z);
    em4.w = lrelu(mx.w + aldv4.w);

    float4 sum4 = make_float4(0.f, 0.f, 0.f, 0.f);
    float accx = 0.f, accy = 0.f;
    const float* hlane = h + hd * 32 + k2;

    for (int c = base; c < end; c += 64) {
        int j = c + lane;
        bool valid = j < end;
        int s; float4 a;
        if (c == base) { s = s0; a = a0; }
        else {
            s = valid ? csr_src[j] : 0;
            a = make_float4(-1e30f, -1e30f, -1e30f, -1e30f);
            if (valid) a = *reinterpret_cast<const float4*>(als4 + (size_t)s * 4);
        }
        float4 ex4 = make_float4(0.f, 0.f, 0.f, 0.f);
        if (valid) {
            ex4.x = __expf(lrelu(a.x + aldv4.x) - em4.x);
            ex4.y = __expf(lrelu(a.y + aldv4.y) - em4.y);
            ex4.z = __expf(lrelu(a.z + aldv4.z) - em4.z);
            ex4.w = __expf(lrelu(a.w + aldv4.w) - em4.w);
            sum4.x += ex4.x; sum4.y += ex4.y; sum4.z += ex4.z; sum4.w += ex4.w;
        }
        *reinterpret_cast<float4*>(&ex_s[w][lane * 4]) = ex4;
        ss_s[w][lane] = s;
        int cnt = min(64, end - c);
        // serial over chunk edges: broadcast ex/s from LDS, gather h row, FMA
#pragma unroll 2
        for (int t = 0; t < cnt; ++t) {
            int ss = ss_s[w][t];
            float exv = ex_s[w][t * 4 + hd];
            float2 hv = *reinterpret_cast<const float2*>(hlane + (size_t)ss * 128);
            accx += exv * hv.x;
            accy += exv * hv.y;
        }
    }

    // per-head denominator via butterfly sum
#pragma unroll
    for (int off = 32; off; off >>= 1) {
        sum4.x += __shfl_xor(sum4.x, off);
        sum4.y += __shfl_xor(sum4.y, off);
        sum4.z += __shfl_xor(sum4.z, off);
        sum4.w += __shfl_xor(sum4.w, off);
    }
    float ssum = (hd == 0) ? sum4.x : (hd == 1) ? sum4.y : (hd == 2) ? sum4.z : sum4.w;
    float inv = 1.0f / (ssum + 1e-16f);
    float2 bv = *reinterpret_cast<const float2*>(bias + hd * 32 + k2);
    float ox = accx * inv + bv.x;
    float oy = accy * inv + bv.y;
    if (applyElu) {
        ox = ox > 0.f ? ox : expm1f(ox);
        oy = oy > 0.f ? oy : expm1f(oy);
    }
    *reinterpret_cast<float2*>(xout + (size_t)v * 128 + hd * 32 + k2) = make_float2(ox, oy);
}

// ---------------- layer 3: GEMM [N,128]x[128,6] with fused al ----------------

__global__ void gemm3_kernel(const float* __restrict__ x, const float* __restrict__ W,
                             const float* __restrict__ as3, const float* __restrict__ ad3,
                             float* __restrict__ h3, float* __restrict__ als3,
                             float* __restrict__ ald3, int N) {
    int n = blockIdx.x * blockDim.x + threadIdx.x;
    if (n >= N) return;
    float acc[6] = {0.f, 0.f, 0.f, 0.f, 0.f, 0.f};
    const float4* xp = reinterpret_cast<const float4*>(x + (size_t)n * 128);
#pragma unroll 4
    for (int k4 = 0; k4 < 32; ++k4) {
        float4 xv = xp[k4];
        const float* w0 = W + (size_t)(k4 * 4) * 6;
#pragma unroll
        for (int j = 0; j < 6; ++j)
            acc[j] += xv.x * w0[j] + xv.y * w0[6 + j] + xv.z * w0[12 + j] + xv.w * w0[18 + j];
    }
    float s = 0.f, d = 0.f;
#pragma unroll
    for (int j = 0; j < 6; ++j) {
        s += acc[j] * as3[j];
        d += acc[j] * ad3[j];
        h3[(size_t)n * 6 + j] = acc[j];
    }
    als3[n] = s;
    ald3[n] = d;
}

__global__ void agg3_kernel(const float* __restrict__ h3, const float* __restrict__ als3,
                            const float* __restrict__ ald3, const int* __restrict__ row_start,
                            const int* __restrict__ csr_src, const float* __restrict__ b3,
                            float* __restrict__ out, int N) {
    int v = blockIdx.x * blockDim.x + threadIdx.x;
    if (v >= N) return;
    int base = row_start[v], end = row_start[v + 1];
    float aldv = ald3[v];
    float mx = -1e30f;
    for (int j = base; j < end; ++j) mx = fmaxf(mx, als3[csr_src[j]]);
    float em = lrelu(mx + aldv);
    float ssum = 0.f;
    float acc[6] = {0.f, 0.f, 0.f, 0.f, 0.f, 0.f};
    for (int j = base; j < end; ++j) {
        int s = csr_src[j];
        float e = lrelu(als3[s] + aldv);
        float ex = __expf(e - em);
        ssum += ex;
        const float* hr = h3 + (size_t)s * 6;
#pragma unroll
        for (int q = 0; q < 6; ++q) acc[q] += ex * hr[q];
    }
    float inv = 1.f / (ssum + 1e-16f);
#pragma unroll
    for (int q = 0; q < 6; ++q) out[(size_t)v * 6 + q] = acc[q] * inv + b3[q];
}

// ---------------- launch ----------------

extern "C" void kernel_launch(void* const* d_in, const int* in_sizes, int n_in,
                              void* d_out, int out_size, void* d_ws, size_t ws_size,
                              hipStream_t stream) {
    const float* x    = (const float*)d_in[0];
    const int*   ei   = (const int*)d_in[1];
    const float* W0   = (const float*)d_in[3];
    const float* as0  = (const float*)d_in[4];
    const float* ad0  = (const float*)d_in[5];
    const float* b0   = (const float*)d_in[6];
    const float* W1   = (const float*)d_in[7];
    const float* as1  = (const float*)d_in[8];
    const float* ad1  = (const float*)d_in[9];
    const float* b1   = (const float*)d_in[10];
    const float* W2   = (const float*)d_in[11];
    const float* as2  = (const float*)d_in[12];
    const float* ad2  = (const float*)d_in[13];
    const float* b2   = (const float*)d_in[14];
    const float* W3   = (const float*)d_in[15];
    const float* as3  = (const float*)d_in[16];
    const float* ad3  = (const float*)d_in[17];
    const float* b3   = (const float*)d_in[18];
    float* out = (float*)d_out;

    int N = in_sizes[0] / IN_CH;
    int E = in_sizes[1] / 2;
    int EN = E + N;

    // workspace layout (256B aligned slices)
    char* p = (char*)d_ws;
    auto alloc = [&](size_t bytes) {
        char* q = p;
        p += (bytes + 255) & ~(size_t)255;
        return q;
    };
    float* hbuf = (float*)alloc((size_t)N * 128 * 4);
    float* xA   = (float*)alloc((size_t)N * 128 * 4);
    float* xB   = (float*)alloc((size_t)N * 128 * 4);
    float* als  = (float*)alloc((size_t)N * 4 * 4);
    float* ald  = (float*)alloc((size_t)N * 4 * 4);
    float* h3   = (float*)alloc((size_t)N * 6 * 4);
    float* als3 = (float*)alloc((size_t)N * 4);
    float* ald3 = (float*)alloc((size_t)N * 4);
    int* row_start = (int*)alloc((size_t)(N + 1) * 4);
    int* cursor    = (int*)alloc((size_t)N * 4);
    int* csr_src   = (int*)alloc((size_t)EN * 4);
    int* blocksum  = (int*)alloc((size_t)4096 * 4);
    (void)ws_size; (void)n_in; (void)out_size;

    // ---- build CSR by dst ----
    hipMemsetAsync(cursor, 0, (size_t)N * 4, stream);
    hist_kernel<<<(EN + 255) / 256, 256, 0, stream>>>(ei, E, N, cursor);
    int nb = (N + SCAN_ELEMS - 1) / SCAN_ELEMS;
    scan_partial<<<nb, 256, 0, stream>>>(cursor, N, blocksum);
    scan_sums<<<1, 256, 0, stream>>>(blocksum, nb);
    scan_apply<<<nb, 256, 0, stream>>>(cursor, N, EN, blocksum, row_start, cursor);
    scatter_kernel<<<(EN + 255) / 256, 256, 0, stream>>>(ei, E, N, cursor, csr_src);

    int gemm_grid = (N + BM - 1) / BM;
    int agg_grid  = (N + 3) / 4;      // 4 waves/block, 1 wave/node
    int n_grid    = (N + 255) / 256;

    // ---- layer 0: 64 -> 4x32, ELU ----
    gemm128_kernel<<<gemm_grid, 256, 0, stream>>>(x, W0, as0, ad0, hbuf, als, ald, N, 64);
    agg_kernel<<<agg_grid, 256, 0, stream>>>(hbuf, als, ald, row_start, csr_src, b0, xA, N, 1);

    // ---- layer 1 ----
    gemm128_kernel<<<gemm_grid, 256, 0, stream>>>(xA, W1, as1, ad1, hbuf, als, ald, N, 128);
    agg_kernel<<<agg_grid, 256, 0, stream>>>(hbuf, als, ald, row_start, csr_src, b1, xB, N, 1);

    // ---- layer 2 ----
    gemm128_kernel<<<gemm_grid, 256, 0, stream>>>(xB, W2, as2, ad2, hbuf, als, ald, N, 128);
    agg_kernel<<<agg_grid, 256, 0, stream>>>(hbuf, als, ald, row_start, csr_src, b2, xA, N, 1);

    // ---- layer 3: 128 -> 6, 1 head, no ELU ----
    gemm3_kernel<<<n_grid, 256, 0, stream>>>(xA, W3, as3, ad3, h3, als3, ald3, N);
    agg3_kernel<<<n_grid, 256, 0, stream>>>(h3, als3, ald3, row_start, csr_src, b3, out, N);
}

// Round 4
// 816.871 us; speedup vs baseline: 1.6454x; 1.0577x over previous
//
#include <hip/hip_runtime.h>
#include <hip/hip_bf16.h>

#define IN_CH 64
#define HID 32
#define HEADS 4
#define OUT_CH 6
#define NEG_SLOPE 0.2f

// ---------------- preprocessing: build dst-CSR ----------------

// 4 edges per thread, int4 loads, batched atomics for latency hiding
__global__ void hist_kernel(const int* __restrict__ ei, int E, int N, int* __restrict__ cnt) {
    int t = blockIdx.x * blockDim.x + threadIdx.x;
    int e0 = t * 4;
    int EN = E + N;
    if (e0 >= EN) return;
    int d[4];
    if (((E & 3) == 0) && (e0 + 3 < E)) {
        int4 dv = *reinterpret_cast<const int4*>(ei + E + e0);
        d[0] = dv.x; d[1] = dv.y; d[2] = dv.z; d[3] = dv.w;
    } else {
#pragma unroll
        for (int k = 0; k < 4; ++k) {
            int e = e0 + k;
            d[k] = (e < E) ? ei[E + e] : (e < EN ? e - E : -1);
        }
    }
#pragma unroll
    for (int k = 0; k < 4; ++k)
        if (d[k] >= 0) atomicAdd(&cnt[d[k]], 1);
}

// ---- multi-block scan: partial sums -> scan sums -> apply ----
#define SCAN_ELEMS 1024

__global__ __launch_bounds__(256) void scan_partial(const int* __restrict__ cnt, int N,
                                                    int* __restrict__ blocksum) {
    __shared__ int red[256];
    int t = threadIdx.x;
    int b0 = blockIdx.x * SCAN_ELEMS;
    int sum = 0;
#pragma unroll
    for (int i = 0; i < SCAN_ELEMS / 256; ++i) {
        int g = b0 + t + i * 256;
        sum += (g < N) ? cnt[g] : 0;
    }
    red[t] = sum;
    __syncthreads();
    for (int off = 128; off; off >>= 1) {
        if (t < off) red[t] += red[t + off];
        __syncthreads();
    }
    if (t == 0) blocksum[blockIdx.x] = red[0];
}

__global__ __launch_bounds__(256) void scan_sums(int* __restrict__ blocksum, int nb) {
    __shared__ int tmp[256];
    int t = threadIdx.x;
    int chunk = (nb + 255) >> 8;
    int s0 = t * chunk, s1 = min(s0 + chunk, nb);
    int sum = 0;
    for (int i = s0; i < s1; ++i) sum += blocksum[i];
    tmp[t] = sum;
    __syncthreads();
    for (int off = 1; off < 256; off <<= 1) {
        int v = (t >= off) ? tmp[t - off] : 0;
        __syncthreads();
        tmp[t] += v;
        __syncthreads();
    }
    int run = (t == 0) ? 0 : tmp[t - 1];
    for (int i = s0; i < s1; ++i) {
        int c = blocksum[i];
        blocksum[i] = run;
        run += c;
    }
}

__global__ __launch_bounds__(256) void scan_apply(const int* __restrict__ cnt, int N, int total,
                                                  const int* __restrict__ blocksum,
                                                  int* __restrict__ row_start,
                                                  int* __restrict__ cursor) {
    __shared__ int tmp[256];
    int t = threadIdx.x;
    int g = blockIdx.x * SCAN_ELEMS + t * 4;
    int4 c = make_int4(0, 0, 0, 0);
    if (g + 3 < N) {
        c = *reinterpret_cast<const int4*>(cnt + g);
    } else {
        if (g + 0 < N) c.x = cnt[g + 0];
        if (g + 1 < N) c.y = cnt[g + 1];
        if (g + 2 < N) c.z = cnt[g + 2];
        if (g + 3 < N) c.w = cnt[g + 3];
    }
    tmp[t] = c.x + c.y + c.z + c.w;
    __syncthreads();
    for (int off = 1; off < 256; off <<= 1) {
        int v = (t >= off) ? tmp[t - off] : 0;
        __syncthreads();
        tmp[t] += v;
        __syncthreads();
    }
    int4 rs;
    rs.x = blocksum[blockIdx.x] + ((t == 0) ? 0 : tmp[t - 1]);
    rs.y = rs.x + c.x;
    rs.z = rs.y + c.y;
    rs.w = rs.z + c.z;
    if (g + 3 < N) {
        *reinterpret_cast<int4*>(row_start + g) = rs;
        *reinterpret_cast<int4*>(cursor + g) = rs;
    } else {
        if (g + 0 < N) { row_start[g + 0] = rs.x; cursor[g + 0] = rs.x; }
        if (g + 1 < N) { row_start[g + 1] = rs.y; cursor[g + 1] = rs.y; }
        if (g + 2 < N) { row_start[g + 2] = rs.z; cursor[g + 2] = rs.z; }
        if (g + 3 < N) { row_start[g + 3] = rs.w; cursor[g + 3] = rs.w; }
    }
    if (blockIdx.x == 0 && t == 0) row_start[N] = total;   // total known analytically (E+N)
}

// 4 edges per thread: issue all 4 atomics before the dependent stores
__global__ void scatter_kernel(const int* __restrict__ ei, int E, int N,
                               int* __restrict__ cursor, int* __restrict__ csr_src) {
    int t = blockIdx.x * blockDim.x + threadIdx.x;
    int e0 = t * 4;
    int EN = E + N;
    if (e0 >= EN) return;
    int s[4], d[4];
    if (((E & 3) == 0) && (e0 + 3 < E)) {
        int4 sv = *reinterpret_cast<const int4*>(ei + e0);
        int4 dv = *reinterpret_cast<const int4*>(ei + E + e0);
        s[0] = sv.x; s[1] = sv.y; s[2] = sv.z; s[3] = sv.w;
        d[0] = dv.x; d[1] = dv.y; d[2] = dv.z; d[3] = dv.w;
    } else {
#pragma unroll
        for (int k = 0; k < 4; ++k) {
            int e = e0 + k;
            if (e < E)       { s[k] = ei[e]; d[k] = ei[E + e]; }
            else if (e < EN) { s[k] = e - E; d[k] = s[k]; }
            else             { s[k] = 0; d[k] = -1; }
        }
    }
    int pos[4];
#pragma unroll
    for (int k = 0; k < 4; ++k)
        pos[k] = (d[k] >= 0) ? atomicAdd(&cursor[d[k]], 1) : 0;
#pragma unroll
    for (int k = 0; k < 4; ++k)
        if (d[k] >= 0) csr_src[pos[k]] = s[k];
}

// ------- GEMM: C[N][128] = A[N][K] @ W[K][128], fused als/ald epilogue -------

#define BM 32
#define BKK 32

__global__ __launch_bounds__(256) void gemm128_kernel(const float* __restrict__ A,
                                                      const float* __restrict__ W,
                                                      const float* __restrict__ avs,
                                                      const float* __restrict__ avd,
                                                      float* __restrict__ C,
                                                      float* __restrict__ als,
                                                      float* __restrict__ ald,
                                                      int N, int K) {
    __shared__ float xs[BM][BKK + 1];
    __shared__ float ws[BKK][128];
    __shared__ float red_s[BM][9];
    __shared__ float red_d[BM][9];
    int tid = threadIdx.x;
    int r  = tid & 31;
    int cg = tid >> 5;            // 0..7, 16-col group
    int row0 = blockIdx.x * BM;

    float acc[16];
#pragma unroll
    for (int j = 0; j < 16; ++j) acc[j] = 0.f;

    for (int kk = 0; kk < K; kk += BKK) {
        {   // x tile: 32 rows x 32 cols, 4 floats/thread
            int lr = tid >> 3, lc = (tid & 7) * 4;
            int gr = row0 + lr;
            float4 v = make_float4(0.f, 0.f, 0.f, 0.f);
            if (gr < N) v = *reinterpret_cast<const float4*>(A + (size_t)gr * K + kk + lc);
            xs[lr][lc + 0] = v.x; xs[lr][lc + 1] = v.y;
            xs[lr][lc + 2] = v.z; xs[lr][lc + 3] = v.w;
        }
        {   // W tile: 32 rows x 128 cols, 16 floats/thread
            int wr = tid >> 3, wc = (tid & 7) * 16;
            const float4* src = reinterpret_cast<const float4*>(W + (size_t)(kk + wr) * 128 + wc);
            float4* dst = reinterpret_cast<float4*>(&ws[wr][wc]);
#pragma unroll
            for (int i = 0; i < 4; ++i) dst[i] = src[i];
        }
        __syncthreads();
#pragma unroll 8
        for (int k = 0; k < BKK; ++k) {
            float xv = xs[r][k];
            const float4* wrow = reinterpret_cast<const float4*>(&ws[k][cg * 16]);
#pragma unroll
            for (int q = 0; q < 4; ++q) {
                float4 wv = wrow[q];
                acc[q * 4 + 0] += xv * wv.x;
                acc[q * 4 + 1] += xv * wv.y;
                acc[q * 4 + 2] += xv * wv.z;
                acc[q * 4 + 3] += xv * wv.w;
            }
        }
        __syncthreads();
    }
    int gr = row0 + r;
    if (gr < N) {
        float4* out = reinterpret_cast<float4*>(C + (size_t)gr * 128 + cg * 16);
#pragma unroll
        for (int q = 0; q < 4; ++q)
            out[q] = make_float4(acc[q * 4 + 0], acc[q * 4 + 1], acc[q * 4 + 2], acc[q * 4 + 3]);
    }
    // fused attention-logit partials: als[n][hd] = sum_d h[n][hd][d]*as[hd][d]
    {
        float ps = 0.f, pd = 0.f;
#pragma unroll
        for (int q = 0; q < 16; ++q) {
            float a = acc[q];
            ps += a * avs[cg * 16 + q];
            pd += a * avd[cg * 16 + q];
        }
        red_s[r][cg] = ps;
        red_d[r][cg] = pd;
        __syncthreads();
        if (gr < N) {
            if (cg < 4) {
                als[(size_t)gr * 4 + cg] = red_s[r][2 * cg] + red_s[r][2 * cg + 1];
            } else {
                int hd = cg - 4;
                ald[(size_t)gr * 4 + hd] = red_d[r][2 * hd] + red_d[r][2 * hd + 1];
            }
        }
    }
}

// ---------------- wave-per-node aggregation (layers 0-2) ----------------

__device__ __forceinline__ float lrelu(float x) { return x > 0.f ? x : NEG_SLOPE * x; }

__global__ __launch_bounds__(256) void agg_kernel(const float* __restrict__ h,
                                                  const float* __restrict__ als4,
                                                  const float* __restrict__ ald4,
                                                  const int* __restrict__ row_start,
                                                  const int* __restrict__ csr_src,
                                                  const float* __restrict__ bias,
                                                  float* __restrict__ xout,
                                                  int N, int applyElu) {
    __shared__ float ex_s[4][256];   // [waveInBlock][edge*4+head]
    __shared__ int   ss_s[4][64];    // [waveInBlock][edge]
    int w = threadIdx.x >> 6;
    int wave = blockIdx.x * 4 + w;
    int lane = threadIdx.x & 63;
    if (wave >= N) return;
    int v = wave;
    int base = row_start[v], end = row_start[v + 1];
    int deg = end - base;
    int hd = lane >> 4;            // head 0..3
    int k2 = (lane & 15) * 2;      // dim pair within head

    float4 aldv4 = *reinterpret_cast<const float4*>(ald4 + (size_t)v * 4);

    // ---- chunk-0 lane-parallel loads (reused below when deg <= 64) ----
    int j0 = base + lane;
    bool v0 = j0 < end;
    int s0 = v0 ? csr_src[j0] : 0;
    float4 a0 = make_float4(-1e30f, -1e30f, -1e30f, -1e30f);
    if (v0) a0 = *reinterpret_cast<const float4*>(als4 + (size_t)s0 * 4);

    float4 mx = a0;
    if (deg > 64) {   // rare slow pre-pass for the max
        for (int j = base + lane + 64; j < end; j += 64) {
            int s = csr_src[j];
            float4 a = *reinterpret_cast<const float4*>(als4 + (size_t)s * 4);
            mx.x = fmaxf(mx.x, a.x); mx.y = fmaxf(mx.y, a.y);
            mx.z = fmaxf(mx.z, a.z); mx.w = fmaxf(mx.w, a.w);
        }
    }
#pragma unroll
    for (int off = 32; off; off >>= 1) {
        mx.x = fmaxf(mx.x, __shfl_xor(mx.x, off));
        mx.y = fmaxf(mx.y, __shfl_xor(mx.y, off));
        mx.z = fmaxf(mx.z, __shfl_xor(mx.z, off));
        mx.w = fmaxf(mx.w, __shfl_xor(mx.w, off));
    }
    // leaky_relu monotone + ald const per node => em = lrelu(max(als)+ald)
    float4 em4;
    em4.x = lrelu(mx.x + aldv4.x);
    em4.y = lrelu(mx.y + aldv4.y);
    em4.z = lrelu(mx.z + aldv4.z);
    em4.w = lrelu(mx.w + aldv4.w);

    float4 sum4 = make_float4(0.f, 0.f, 0.f, 0.f);
    float accx = 0.f, accy = 0.f;
    float accx2 = 0.f, accy2 = 0.f;
    const float* hlane = h + hd * 32 + k2;

    for (int c = base; c < end; c += 64) {
        int j = c + lane;
        bool valid = j < end;
        int s; float4 a;
        if (c == base) { s = s0; a = a0; }
        else {
            s = valid ? csr_src[j] : 0;
            a = make_float4(-1e30f, -1e30f, -1e30f, -1e30f);
            if (valid) a = *reinterpret_cast<const float4*>(als4 + (size_t)s * 4);
        }
        float4 ex4 = make_float4(0.f, 0.f, 0.f, 0.f);
        if (valid) {
            ex4.x = __expf(lrelu(a.x + aldv4.x) - em4.x);
            ex4.y = __expf(lrelu(a.y + aldv4.y) - em4.y);
            ex4.z = __expf(lrelu(a.z + aldv4.z) - em4.z);
            ex4.w = __expf(lrelu(a.w + aldv4.w) - em4.w);
            sum4.x += ex4.x; sum4.y += ex4.y; sum4.z += ex4.z; sum4.w += ex4.w;
        }
        *reinterpret_cast<float4*>(&ex_s[w][lane * 4]) = ex4;
        ss_s[w][lane] = s;
        int cnt = min(64, end - c);
        // serial over chunk edges: unroll 4, two accumulator chains -> 4 gathers in flight
        int t = 0;
        for (; t + 3 < cnt; t += 4) {
            int ss0 = ss_s[w][t + 0];
            int ss1 = ss_s[w][t + 1];
            int ss2 = ss_s[w][t + 2];
            int ss3 = ss_s[w][t + 3];
            float e0 = ex_s[w][(t + 0) * 4 + hd];
            float e1 = ex_s[w][(t + 1) * 4 + hd];
            float e2 = ex_s[w][(t + 2) * 4 + hd];
            float e3 = ex_s[w][(t + 3) * 4 + hd];
            float2 h0 = *reinterpret_cast<const float2*>(hlane + (size_t)ss0 * 128);
            float2 h1 = *reinterpret_cast<const float2*>(hlane + (size_t)ss1 * 128);
            float2 h2 = *reinterpret_cast<const float2*>(hlane + (size_t)ss2 * 128);
            float2 h3 = *reinterpret_cast<const float2*>(hlane + (size_t)ss3 * 128);
            accx  += e0 * h0.x; accy  += e0 * h0.y;
            accx2 += e1 * h1.x; accy2 += e1 * h1.y;
            accx  += e2 * h2.x; accy  += e2 * h2.y;
            accx2 += e3 * h3.x; accy2 += e3 * h3.y;
        }
        for (; t < cnt; ++t) {
            int ss = ss_s[w][t];
            float exv = ex_s[w][t * 4 + hd];
            float2 hv = *reinterpret_cast<const float2*>(hlane + (size_t)ss * 128);
            accx += exv * hv.x;
            accy += exv * hv.y;
        }
    }
    accx += accx2;
    accy += accy2;

    // per-head denominator via butterfly sum
#pragma unroll
    for (int off = 32; off; off >>= 1) {
        sum4.x += __shfl_xor(sum4.x, off);
        sum4.y += __shfl_xor(sum4.y, off);
        sum4.z += __shfl_xor(sum4.z, off);
        sum4.w += __shfl_xor(sum4.w, off);
    }
    float ssum = (hd == 0) ? sum4.x : (hd == 1) ? sum4.y : (hd == 2) ? sum4.z : sum4.w;
    float inv = 1.0f / (ssum + 1e-16f);
    float2 bv = *reinterpret_cast<const float2*>(bias + hd * 32 + k2);
    float ox = accx * inv + bv.x;
    float oy = accy * inv + bv.y;
    if (applyElu) {
        ox = ox > 0.f ? ox : expm1f(ox);
        oy = oy > 0.f ? oy : expm1f(oy);
    }
    *reinterpret_cast<float2*>(xout + (size_t)v * 128 + hd * 32 + k2) = make_float2(ox, oy);
}

// ---------------- layer 3: GEMM [N,128]x[128,6] with fused al ----------------

__global__ void gemm3_kernel(const float* __restrict__ x, const float* __restrict__ W,
                             const float* __restrict__ as3, const float* __restrict__ ad3,
                             float* __restrict__ h3, float* __restrict__ als3,
                             float* __restrict__ ald3, int N) {
    int n = blockIdx.x * blockDim.x + threadIdx.x;
    if (n >= N) return;
    float acc[6] = {0.f, 0.f, 0.f, 0.f, 0.f, 0.f};
    const float4* xp = reinterpret_cast<const float4*>(x + (size_t)n * 128);
#pragma unroll 4
    for (int k4 = 0; k4 < 32; ++k4) {
        float4 xv = xp[k4];
        const float* w0 = W + (size_t)(k4 * 4) * 6;
#pragma unroll
        for (int j = 0; j < 6; ++j)
            acc[j] += xv.x * w0[j] + xv.y * w0[6 + j] + xv.z * w0[12 + j] + xv.w * w0[18 + j];
    }
    float s = 0.f, d = 0.f;
#pragma unroll
    for (int j = 0; j < 6; ++j) {
        s += acc[j] * as3[j];
        d += acc[j] * ad3[j];
        h3[(size_t)n * 6 + j] = acc[j];
    }
    als3[n] = s;
    ald3[n] = d;
}

__global__ void agg3_kernel(const float* __restrict__ h3, const float* __restrict__ als3,
                            const float* __restrict__ ald3, const int* __restrict__ row_start,
                            const int* __restrict__ csr_src, const float* __restrict__ b3,
                            float* __restrict__ out, int N) {
    int v = blockIdx.x * blockDim.x + threadIdx.x;
    if (v >= N) return;
    int base = row_start[v], end = row_start[v + 1];
    float aldv = ald3[v];
    float mx = -1e30f;
    for (int j = base; j < end; ++j) mx = fmaxf(mx, als3[csr_src[j]]);
    float em = lrelu(mx + aldv);
    float ssum = 0.f;
    float acc[6] = {0.f, 0.f, 0.f, 0.f, 0.f, 0.f};
    for (int j = base; j < end; ++j) {
        int s = csr_src[j];
        float e = lrelu(als3[s] + aldv);
        float ex = __expf(e - em);
        ssum += ex;
        const float* hr = h3 + (size_t)s * 6;
#pragma unroll
        for (int q = 0; q < 6; ++q) acc[q] += ex * hr[q];
    }
    float inv = 1.f / (ssum + 1e-16f);
#pragma unroll
    for (int q = 0; q < 6; ++q) out[(size_t)v * 6 + q] = acc[q] * inv + b3[q];
}

// ---------------- launch ----------------

extern "C" void kernel_launch(void* const* d_in, const int* in_sizes, int n_in,
                              void* d_out, int out_size, void* d_ws, size_t ws_size,
                              hipStream_t stream) {
    const float* x    = (const float*)d_in[0];
    const int*   ei   = (const int*)d_in[1];
    const float* W0   = (const float*)d_in[3];
    const float* as0  = (const float*)d_in[4];
    const float* ad0  = (const float*)d_in[5];
    const float* b0   = (const float*)d_in[6];
    const float* W1   = (const float*)d_in[7];
    const float* as1  = (const float*)d_in[8];
    const float* ad1  = (const float*)d_in[9];
    const float* b1   = (const float*)d_in[10];
    const float* W2   = (const float*)d_in[11];
    const float* as2  = (const float*)d_in[12];
    const float* ad2  = (const float*)d_in[13];
    const float* b2   = (const float*)d_in[14];
    const float* W3   = (const float*)d_in[15];
    const float* as3  = (const float*)d_in[16];
    const float* ad3  = (const float*)d_in[17];
    const float* b3   = (const float*)d_in[18];
    float* out = (float*)d_out;

    int N = in_sizes[0] / IN_CH;
    int E = in_sizes[1] / 2;
    int EN = E + N;

    // workspace layout (256B aligned slices)
    char* p = (char*)d_ws;
    auto alloc = [&](size_t bytes) {
        char* q = p;
        p += (bytes + 255) & ~(size_t)255;
        return q;
    };
    float* hbuf = (float*)alloc((size_t)N * 128 * 4);
    float* xA   = (float*)alloc((size_t)N * 128 * 4);
    float* xB   = (float*)alloc((size_t)N * 128 * 4);
    float* als  = (float*)alloc((size_t)N * 4 * 4);
    float* ald  = (float*)alloc((size_t)N * 4 * 4);
    float* h3   = (float*)alloc((size_t)N * 6 * 4);
    float* als3 = (float*)alloc((size_t)N * 4);
    float* ald3 = (float*)alloc((size_t)N * 4);
    int* row_start = (int*)alloc((size_t)(N + 1) * 4);
    int* cursor    = (int*)alloc((size_t)N * 4);
    int* csr_src   = (int*)alloc((size_t)EN * 4);
    int* blocksum  = (int*)alloc((size_t)4096 * 4);
    (void)ws_size; (void)n_in; (void)out_size;

    // ---- build CSR by dst ----
    hipMemsetAsync(cursor, 0, (size_t)N * 4, stream);
    int ethreads = (EN + 3) / 4;
    hist_kernel<<<(ethreads + 255) / 256, 256, 0, stream>>>(ei, E, N, cursor);
    int nb = (N + SCAN_ELEMS - 1) / SCAN_ELEMS;
    scan_partial<<<nb, 256, 0, stream>>>(cursor, N, blocksum);
    scan_sums<<<1, 256, 0, stream>>>(blocksum, nb);
    scan_apply<<<nb, 256, 0, stream>>>(cursor, N, EN, blocksum, row_start, cursor);
    scatter_kernel<<<(ethreads + 255) / 256, 256, 0, stream>>>(ei, E, N, cursor, csr_src);

    int gemm_grid = (N + BM - 1) / BM;
    int agg_grid  = (N + 3) / 4;      // 4 waves/block, 1 wave/node
    int n_grid    = (N + 255) / 256;

    // ---- layer 0: 64 -> 4x32, ELU ----
    gemm128_kernel<<<gemm_grid, 256, 0, stream>>>(x, W0, as0, ad0, hbuf, als, ald, N, 64);
    agg_kernel<<<agg_grid, 256, 0, stream>>>(hbuf, als, ald, row_start, csr_src, b0, xA, N, 1);

    // ---- layer 1 ----
    gemm128_kernel<<<gemm_grid, 256, 0, stream>>>(xA, W1, as1, ad1, hbuf, als, ald, N, 128);
    agg_kernel<<<agg_grid, 256, 0, stream>>>(hbuf, als, ald, row_start, csr_src, b1, xB, N, 1);

    // ---- layer 2 ----
    gemm128_kernel<<<gemm_grid, 256, 0, stream>>>(xB, W2, as2, ad2, hbuf, als, ald, N, 128);
    agg_kernel<<<agg_grid, 256, 0, stream>>>(hbuf, als, ald, row_start, csr_src, b2, xA, N, 1);

    // ---- layer 3: 128 -> 6, 1 head, no ELU ----
    gemm3_kernel<<<n_grid, 256, 0, stream>>>(xA, W3, as3, ad3, h3, als3, ald3, N);
    agg3_kernel<<<n_grid, 256, 0, stream>>>(h3, als3, ald3, row_start, csr_src, b3, out, N);
}